// Round 2
// baseline (315.169 us; speedup 1.0000x reference)
//
#include <hip/hip_runtime.h>

// IntClassifier: sum-pool over L + dead_shift(4) -> int GEMM -> dead_shift(11)+clamp -> int8 (written as int32)
// B=256, C=2048, L=512, N=1000
#define BB 256
#define CC 2048
#define LL 512
#define NN 1000
#define FINAL_SHIFT 4
#define FC_SHIFT 11

#define TB 32      // b-tile
#define TN 64      // n-tile
#define BK 64      // k-chunk staged in LDS

__device__ __forceinline__ int dead_shift_i(int x, int shift) {
    int thr = 1 << shift;
    int ax = x < 0 ? -x : x;
    x = (ax >= thr) ? x : 0;
    return x >> shift;   // arithmetic shift on signed int32
}

// ---------------- Stage 1: sum-pool over L, dead_shift(4) ----------------
// One wave per (b,c) row of 512 int32. Lanes load 2x int4 (coalesced 2KB/wave),
// butterfly-reduce across 64 lanes, lane 0 writes acc[b*C+c].
__global__ __launch_bounds__(256) void pool_kernel(const int* __restrict__ x,
                                                   int* __restrict__ acc) {
    int wave = threadIdx.x >> 6;         // 0..3
    int lane = threadIdx.x & 63;
    long long row = (long long)blockIdx.x * 4 + wave;   // < B*C = 524288
    const int* p = x + row * LL;
    int4 v0 = *(const int4*)(p + lane * 4);
    int4 v1 = *(const int4*)(p + 256 + lane * 4);
    int s = v0.x + v0.y + v0.z + v0.w + v1.x + v1.y + v1.z + v1.w;
#pragma unroll
    for (int m = 32; m >= 1; m >>= 1) s += __shfl_xor(s, m, 64);
    if (lane == 0) acc[row] = dead_shift_i(s, FINAL_SHIFT);
}

// ---------------- Stage 2: fused int32 GEMM + dead_shift(11) + clamp ----------------
// y[b][n] = sum_c acc[b][c] * w[n][c]. Block computes a 32(b) x 64(n) tile over
// the full K=2048, then applies shift/clamp and writes int32 to out.
__global__ __launch_bounds__(256) void gemm_kernel(const int* __restrict__ acc,
                                                   const int* __restrict__ w,
                                                   int* __restrict__ out) {
    __shared__ int As[TB][BK + 1];    // +1 pad breaks pow2 stride
    __shared__ int Ws[BK][TN + 4];    // +4 pad keeps int4 alignment, breaks pow2 stride

    int b0 = blockIdx.x * TB;         // 0..224
    int n0 = blockIdx.y * TN;         // 0..960

    int t  = threadIdx.x;
    int tx = t & 15;                  // n-dim: 16 threads x 4 n each
    int ty = t >> 4;                  // b-dim: 16 threads x 2 b each

    int r[2][4] = {{0, 0, 0, 0}, {0, 0, 0, 0}};

    for (int k0 = 0; k0 < CC; k0 += BK) {
        // --- stage A tile: 32x64 ints, 8 consecutive ints per thread ---
        {
            int idx = t * 8;
            int b   = idx >> 6;       // 0..31
            int kk  = idx & 63;
            const int* src = acc + (long long)(b0 + b) * CC + k0 + kk;
            int4 u0 = *(const int4*)(src);
            int4 u1 = *(const int4*)(src + 4);
            As[b][kk + 0] = u0.x; As[b][kk + 1] = u0.y;
            As[b][kk + 2] = u0.z; As[b][kk + 3] = u0.w;
            As[b][kk + 4] = u1.x; As[b][kk + 5] = u1.y;
            As[b][kk + 6] = u1.z; As[b][kk + 7] = u1.w;
        }
        // --- stage W tile transposed: Ws[kk][n] = w[n0+n][k0+kk] ---
#pragma unroll
        for (int rep = 0; rep < 4; ++rep) {
            int n  = rep * 16 + ty;   // 0..63
            int kk = tx * 4;          // 0..60
            int nn = n0 + n;
            int4 u = make_int4(0, 0, 0, 0);
            if (nn < NN) u = *(const int4*)(w + (long long)nn * CC + k0 + kk);
            Ws[kk + 0][n] = u.x; Ws[kk + 1][n] = u.y;
            Ws[kk + 2][n] = u.z; Ws[kk + 3][n] = u.w;
        }
        __syncthreads();

#pragma unroll
        for (int kk = 0; kk < BK; ++kk) {
            int4 wv = *(const int4*)&Ws[kk][tx * 4];
            int a0 = As[ty * 2 + 0][kk];
            int a1 = As[ty * 2 + 1][kk];
            r[0][0] += a0 * wv.x; r[0][1] += a0 * wv.y; r[0][2] += a0 * wv.z; r[0][3] += a0 * wv.w;
            r[1][0] += a1 * wv.x; r[1][1] += a1 * wv.y; r[1][2] += a1 * wv.z; r[1][3] += a1 * wv.w;
        }
        __syncthreads();
    }

    // fused epilogue: dead_shift(11) + clamp to int8 range, store int32
#pragma unroll
    for (int i = 0; i < 2; ++i) {
#pragma unroll
        for (int j = 0; j < 4; ++j) {
            int n = n0 + tx * 4 + j;
            if (n < NN) {
                int v = dead_shift_i(r[i][j], FC_SHIFT);
                v = min(127, max(-128, v));
                out[(long long)(b0 + ty * 2 + i) * NN + n] = v;
            }
        }
    }
}

extern "C" void kernel_launch(void* const* d_in, const int* in_sizes, int n_in,
                              void* d_out, int out_size, void* d_ws, size_t ws_size,
                              hipStream_t stream) {
    const int* x = (const int*)d_in[0];     // (B, C, L) int32
    const int* w = (const int*)d_in[1];     // (N, C) int32
    int* out = (int*)d_out;                 // (B, N) int32 values in [-128,127]

    int* acc = (int*)d_ws;                  // B*C ints = 2 MB

    pool_kernel<<<(BB * CC) / 4, 256, 0, stream>>>(x, acc);

    dim3 g2(BB / TB, (NN + TN - 1) / TN);   // (8, 16) = 128 blocks
    gemm_kernel<<<g2, 256, 0, stream>>>(acc, w, out);
}

// Round 3
// 236.095 us; speedup vs baseline: 1.3349x; 1.3349x over previous
//
#include <hip/hip_runtime.h>

// IntClassifier: sum-pool over L + dead_shift(4) -> int GEMM -> dead_shift(11)+clamp -> int8 (as int32)
// B=256, C=2048, L=512, N=1000
#define BB 256
#define CC 2048
#define LL 512
#define NN 1000
#define FINAL_SHIFT 4
#define FC_SHIFT 11

#define TB 32      // b-tile
#define TN 64      // n-tile
#define BK 64      // k-chunk staged in LDS

__device__ __forceinline__ int dead_shift_i(int x, int shift) {
    int thr = 1 << shift;
    int ax = x < 0 ? -x : x;
    x = (ax >= thr) ? x : 0;
    return x >> shift;   // arithmetic shift on signed int32
}

// ---------------- Stage 1: sum-pool over L, dead_shift(4) ----------------
// 16-lane row groups: each wave covers 4 contiguous rows (8 KB). Each lane
// issues 8 independent int4 loads (high MLP), sums 32 ints locally, then a
// 4-step shfl reduce within its 16-lane group. Group leaders (lanes 0,16,32,48)
// write 4 consecutive dwords of acc.
__global__ __launch_bounds__(256) void pool_kernel(const int* __restrict__ x,
                                                   int* __restrict__ acc) {
    int wave = threadIdx.x >> 6;          // 0..3
    int lane = threadIdx.x & 63;
    int g    = lane >> 4;                 // row within wave: 0..3
    int j    = lane & 15;                 // lane within row group
    long long rowBase = ((long long)blockIdx.x * 4 + wave) * 4;   // 4 rows per wave
    const int* p = x + (rowBase + g) * (long long)LL;

    int4 v[8];
#pragma unroll
    for (int c = 0; c < 8; ++c)
        v[c] = *(const int4*)(p + c * 64 + j * 4);   // 4x256B contiguous chunks/instr

    int s = 0;
#pragma unroll
    for (int c = 0; c < 8; ++c) s += v[c].x + v[c].y + v[c].z + v[c].w;

    s += __shfl_xor(s, 1, 64);
    s += __shfl_xor(s, 2, 64);
    s += __shfl_xor(s, 4, 64);
    s += __shfl_xor(s, 8, 64);

    if (j == 0) acc[rowBase + g] = dead_shift_i(s, FINAL_SHIFT);
}

// ---------------- Stage 2: int32 GEMM, K-split partials ----------------
// y[b][n] = sum_c acc[b][c] * w[n][c]. Block computes a 32(b) x 64(n) tile over
// a CC/Z slice of K (blockIdx.z), writes int32 partials [z][b][n].
__global__ __launch_bounds__(256) void gemm_kernel(const int* __restrict__ acc,
                                                   const int* __restrict__ w,
                                                   int* __restrict__ partial,
                                                   int kch) {
    __shared__ int As[TB][BK + 1];    // +1 pad breaks pow2 stride
    __shared__ int Ws[BK][TN + 4];    // +4 pad keeps int4 alignment, breaks pow2 stride

    int b0 = blockIdx.x * TB;         // 0..224
    int n0 = blockIdx.y * TN;         // 0..960
    int kbase = blockIdx.z * kch;

    int t  = threadIdx.x;
    int tx = t & 15;                  // n-dim: 16 threads x 4 n each
    int ty = t >> 4;                  // b-dim: 16 threads x 2 b each

    int r[2][4] = {{0, 0, 0, 0}, {0, 0, 0, 0}};

    for (int k0 = kbase; k0 < kbase + kch; k0 += BK) {
        // --- stage A tile: 32x64 ints, 8 consecutive ints per thread ---
        {
            int idx = t * 8;
            int b   = idx >> 6;       // 0..31
            int kk  = idx & 63;
            const int* src = acc + (long long)(b0 + b) * CC + k0 + kk;
            int4 u0 = *(const int4*)(src);
            int4 u1 = *(const int4*)(src + 4);
            As[b][kk + 0] = u0.x; As[b][kk + 1] = u0.y;
            As[b][kk + 2] = u0.z; As[b][kk + 3] = u0.w;
            As[b][kk + 4] = u1.x; As[b][kk + 5] = u1.y;
            As[b][kk + 6] = u1.z; As[b][kk + 7] = u1.w;
        }
        // --- stage W tile transposed: Ws[kk][n] = w[n0+n][k0+kk] ---
#pragma unroll
        for (int rep = 0; rep < 4; ++rep) {
            int n  = rep * 16 + ty;   // 0..63
            int kk = tx * 4;          // 0..60
            int nn = n0 + n;
            int4 u = make_int4(0, 0, 0, 0);
            if (nn < NN) u = *(const int4*)(w + (long long)nn * CC + k0 + kk);
            Ws[kk + 0][n] = u.x; Ws[kk + 1][n] = u.y;
            Ws[kk + 2][n] = u.z; Ws[kk + 3][n] = u.w;
        }
        __syncthreads();

#pragma unroll
        for (int kk = 0; kk < BK; ++kk) {
            int4 wv = *(const int4*)&Ws[kk][tx * 4];
            int a0 = As[ty * 2 + 0][kk];
            int a1 = As[ty * 2 + 1][kk];
            r[0][0] += a0 * wv.x; r[0][1] += a0 * wv.y; r[0][2] += a0 * wv.z; r[0][3] += a0 * wv.w;
            r[1][0] += a1 * wv.x; r[1][1] += a1 * wv.y; r[1][2] += a1 * wv.z; r[1][3] += a1 * wv.w;
        }
        __syncthreads();
    }

    long long base = (long long)blockIdx.z * BB * NN;
#pragma unroll
    for (int i = 0; i < 2; ++i) {
#pragma unroll
        for (int j = 0; j < 4; ++j) {
            int n = n0 + tx * 4 + j;
            if (n < NN)
                partial[base + (long long)(b0 + ty * 2 + i) * NN + n] = r[i][j];
        }
    }
}

// ---------------- Stage 3: reduce K-splits, dead_shift(11), clamp ----------------
__global__ __launch_bounds__(256) void epilogue_kernel(const int* __restrict__ partial,
                                                       int* __restrict__ out, int z) {
    int idx = blockIdx.x * 256 + threadIdx.x;
    if (idx >= BB * NN) return;
    int s = 0;
    for (int i = 0; i < z; ++i) s += partial[(long long)i * BB * NN + idx];
    int v = dead_shift_i(s, FC_SHIFT);
    v = min(127, max(-128, v));
    out[idx] = v;
}

extern "C" void kernel_launch(void* const* d_in, const int* in_sizes, int n_in,
                              void* d_out, int out_size, void* d_ws, size_t ws_size,
                              hipStream_t stream) {
    const int* x = (const int*)d_in[0];     // (B, C, L) int32
    const int* w = (const int*)d_in[1];     // (N, C) int32
    int* out = (int*)d_out;                 // (B, N) int32 values in [-128,127]

    int* acc     = (int*)d_ws;              // B*C ints = 2 MB
    int* partial = acc + (size_t)BB * CC;   // Z*B*N ints

    // K-split factor: prefer 4 (needs 2MB + 4MB ws); fall back to 1 (3MB).
    size_t need4 = ((size_t)BB * CC + 4ull * BB * NN) * 4;
    int Z = (ws_size >= need4) ? 4 : 1;
    int kch = CC / Z;

    pool_kernel<<<(BB * CC) / 16, 256, 0, stream>>>(x, acc);

    dim3 g2(BB / TB, (NN + TN - 1) / TN, Z);   // (8, 16, Z)
    gemm_kernel<<<g2, 256, 0, stream>>>(acc, w, partial, kch);

    epilogue_kernel<<<(BB * NN + 255) / 256, 256, 0, stream>>>(partial, out, Z);
}

// Round 4
// 232.673 us; speedup vs baseline: 1.3546x; 1.0147x over previous
//
#include <hip/hip_runtime.h>

// IntClassifier: sum-pool over L + dead_shift(4) -> int GEMM -> dead_shift(11)+clamp -> int8 (as int32)
// B=256, C=2048, L=512, N=1000
#define BB 256
#define CC 2048
#define LL 512
#define NN 1000
#define FINAL_SHIFT 4
#define FC_SHIFT 11

// GEMM tiling
#define TBB 64     // b per block
#define TNN 128    // n per block
#define BK 64      // k per LDS stage
#define AP 76      // As row stride (ints): 19 granules -> 2-way max on reads/writes
#define WP 132     // Ws row stride (ints): 33 granules, 16B-aligned rows

__device__ __forceinline__ int dead_shift_i(int x, int shift) {
    int thr = 1 << shift;
    int ax = x < 0 ? -x : x;
    x = (ax >= thr) ? x : 0;
    return x >> shift;   // arithmetic shift on signed int32
}

// ---------------- Stage 1: sum-pool over L, dead_shift(4) ----------------
// Each wave: 8 rows (two independent 4-row quads). 16-lane groups per row,
// 16 int4 loads in flight per lane before any reduce; 4-step shfl per quad.
__global__ __launch_bounds__(256) void pool_kernel(const int* __restrict__ x,
                                                   int* __restrict__ acc) {
    int wave = threadIdx.x >> 6;
    int lane = threadIdx.x & 63;
    int g = lane >> 4;                    // 0..3: row within quad
    int j = lane & 15;                    // lane within 16-lane row group
    long long rowBase = ((long long)blockIdx.x * 4 + wave) * 8;
    const int* pA = x + (rowBase + g) * (long long)LL;
    const int* pB = x + (rowBase + 4 + g) * (long long)LL;

    int4 v[8], u[8];
#pragma unroll
    for (int c = 0; c < 8; ++c) v[c] = *(const int4*)(pA + c * 64 + j * 4);
#pragma unroll
    for (int c = 0; c < 8; ++c) u[c] = *(const int4*)(pB + c * 64 + j * 4);

    int sA = 0, sB = 0;
#pragma unroll
    for (int c = 0; c < 8; ++c) sA += v[c].x + v[c].y + v[c].z + v[c].w;
#pragma unroll
    for (int c = 0; c < 8; ++c) sB += u[c].x + u[c].y + u[c].z + u[c].w;

    sA += __shfl_xor(sA, 1, 64);  sB += __shfl_xor(sB, 1, 64);
    sA += __shfl_xor(sA, 2, 64);  sB += __shfl_xor(sB, 2, 64);
    sA += __shfl_xor(sA, 4, 64);  sB += __shfl_xor(sB, 4, 64);
    sA += __shfl_xor(sA, 8, 64);  sB += __shfl_xor(sB, 8, 64);

    if (j == 0) {
        acc[rowBase + g]     = dead_shift_i(sA, FINAL_SHIFT);
        acc[rowBase + 4 + g] = dead_shift_i(sB, FINAL_SHIFT);
    }
}

// ---------------- Stage 2: int32 GEMM, K-split partials ----------------
// Block: 64(b) x 128(n) tile over kch of K. Thread: 4b x 8n via __mul24 MACs
// (A fits 13 bits after dead_shift(4), W fits 8 bits -> i24 exact).
// Ws stored transposed with XOR swizzle col ^= ((kk>>3)&3)<<2 (16B-preserving).
__global__ __launch_bounds__(256) void gemm_kernel(const int* __restrict__ acc,
                                                   const int* __restrict__ w,
                                                   int* __restrict__ partial,
                                                   int kch) {
    __shared__ int As[TBB][AP];
    __shared__ int Ws[BK][WP];

    int b0 = blockIdx.x * TBB;
    int n0 = blockIdx.y * TNN;
    int kbase = blockIdx.z * kch;

    int t  = threadIdx.x;
    int tx = t & 15;                  // n-dim
    int ty = t >> 4;                  // b-dim

    int r[4][8];
#pragma unroll
    for (int bi = 0; bi < 4; ++bi)
#pragma unroll
        for (int j = 0; j < 8; ++j) r[bi][j] = 0;

    for (int k0 = kbase; k0 < kbase + kch; k0 += BK) {
        // --- stage A: 64b x 64kk; thread loads 4 int4 from one row ---
        {
            int b  = t >> 2;              // 0..63
            int kq = (t & 3) * 16;        // 0,16,32,48
            const int* src = acc + (long long)(b0 + b) * CC + k0 + kq;
            int4 u0 = *(const int4*)(src + 0);
            int4 u1 = *(const int4*)(src + 4);
            int4 u2 = *(const int4*)(src + 8);
            int4 u3 = *(const int4*)(src + 12);
            *(int4*)&As[b][kq + 0]  = u0;
            *(int4*)&As[b][kq + 4]  = u1;
            *(int4*)&As[b][kq + 8]  = u2;
            *(int4*)&As[b][kq + 12] = u3;
        }
        // --- stage W transposed + swizzled: Ws[kk][n ^ sw], sw = ((kk>>3)&3)<<2 ---
        {
            int kk = tx * 4;
            int sw = ((tx >> 1) & 3) << 2;   // == ((kk+i)>>3)&3 <<2 for i<4
#pragma unroll
            for (int rep = 0; rep < 8; ++rep) {
                int n  = rep * 16 + ty;
                int nn = n0 + n;
                int4 uw = make_int4(0, 0, 0, 0);
                if (nn < NN) uw = *(const int4*)(w + (long long)nn * CC + k0 + kk);
                int c = n ^ sw;
                Ws[kk + 0][c] = uw.x;
                Ws[kk + 1][c] = uw.y;
                Ws[kk + 2][c] = uw.z;
                Ws[kk + 3][c] = uw.w;
            }
        }
        __syncthreads();

#pragma unroll
        for (int kk4 = 0; kk4 < BK; kk4 += 4) {
            int4 a[4];
#pragma unroll
            for (int bi = 0; bi < 4; ++bi)
                a[bi] = *(const int4*)&As[ty * 4 + bi][kk4];
#pragma unroll
            for (int uu = 0; uu < 4; ++uu) {
                int kk  = kk4 + uu;
                int swr = ((kk >> 3) & 3) << 2;
                int c0  = (tx * 4) ^ swr;
                int4 w0 = *(const int4*)&Ws[kk][c0];
                int4 w1 = *(const int4*)&Ws[kk][64 + c0];
#pragma unroll
                for (int bi = 0; bi < 4; ++bi) {
                    int av = (uu == 0) ? a[bi].x : (uu == 1) ? a[bi].y
                           : (uu == 2) ? a[bi].z : a[bi].w;
                    r[bi][0] += __mul24(av, w0.x);
                    r[bi][1] += __mul24(av, w0.y);
                    r[bi][2] += __mul24(av, w0.z);
                    r[bi][3] += __mul24(av, w0.w);
                    r[bi][4] += __mul24(av, w1.x);
                    r[bi][5] += __mul24(av, w1.y);
                    r[bi][6] += __mul24(av, w1.z);
                    r[bi][7] += __mul24(av, w1.w);
                }
            }
        }
        __syncthreads();
    }

    long long base = (long long)blockIdx.z * BB * NN;
#pragma unroll
    for (int bi = 0; bi < 4; ++bi) {
        int b = b0 + ty * 4 + bi;
#pragma unroll
        for (int j = 0; j < 8; ++j) {
            int n = n0 + ((j < 4) ? (tx * 4 + j) : (64 + tx * 4 + (j - 4)));
            if (n < NN)
                partial[base + (long long)b * NN + n] = r[bi][j];
        }
    }
}

// ---------------- Stage 3: reduce K-splits, dead_shift(11), clamp ----------------
__global__ __launch_bounds__(256) void epilogue_kernel(const int* __restrict__ partial,
                                                       int* __restrict__ out, int z) {
    int idx = blockIdx.x * 256 + threadIdx.x;
    if (idx >= BB * NN) return;
    int s = 0;
    for (int i = 0; i < z; ++i) s += partial[(long long)i * BB * NN + idx];
    int v = dead_shift_i(s, FC_SHIFT);
    v = min(127, max(-128, v));
    out[idx] = v;
}

extern "C" void kernel_launch(void* const* d_in, const int* in_sizes, int n_in,
                              void* d_out, int out_size, void* d_ws, size_t ws_size,
                              hipStream_t stream) {
    const int* x = (const int*)d_in[0];     // (B, C, L) int32
    const int* w = (const int*)d_in[1];     // (N, C) int32
    int* out = (int*)d_out;                 // (B, N) int32 values in [-128,127]

    int* acc     = (int*)d_ws;              // B*C ints = 2 MB
    int* partial = acc + (size_t)BB * CC;   // Z*B*N ints

    // pick largest K-split fitting the workspace (16 -> 18 MB)
    size_t accBytes = (size_t)BB * CC * 4;
    int Z = 16;
    while (Z > 1 && ws_size < accBytes + (size_t)Z * BB * NN * 4) Z >>= 1;
    int kch = CC / Z;

    pool_kernel<<<(BB * CC) / 32, 256, 0, stream>>>(x, acc);

    dim3 g2(BB / TBB, (NN + TNN - 1) / TNN, Z);   // (4, 8, Z)
    gemm_kernel<<<g2, 256, 0, stream>>>(acc, w, partial, kch);

    epilogue_kernel<<<(BB * NN + 255) / 256, 256, 0, stream>>>(partial, out, Z);
}

// Round 5
// 226.601 us; speedup vs baseline: 1.3909x; 1.0268x over previous
//
#include <hip/hip_runtime.h>

// IntClassifier: sum-pool over L + dead_shift(4) -> int GEMM (i8 dot4, hi/lo split)
// -> dead_shift(11)+clamp -> int8 (as int32). B=256, C=2048, L=512, N=1000
#define BB 256
#define CC 2048
#define LL 512
#define NN 1000
#define FINAL_SHIFT 4
#define FC_SHIFT 11

// GEMM tiling
#define TBB 64       // b per block
#define TNN 128      // n per block
#define BK 64        // k per LDS stage
#define NKQ 16       // BK/4 packed dwords per row
#define ASTR 36      // As row stride: 16 hi + 16 lo + 4 pad
#define WSTR 132     // Ws row stride: 128 + 4 pad

#if __has_builtin(__builtin_amdgcn_sdot4)
#define DOT4(a, b, c) __builtin_amdgcn_sdot4((a), (b), (c), false)
#else
static __device__ __forceinline__ int dot4_fb(int a, int b, int c) {
#pragma unroll
    for (int j = 0; j < 4; ++j) {
        int av = (a << (24 - 8 * j)) >> 24;
        int bv = (b << (24 - 8 * j)) >> 24;
        c += av * bv;
    }
    return c;
}
#define DOT4(a, b, c) dot4_fb((a), (b), (c))
#endif

__device__ __forceinline__ int dead_shift_i(int x, int shift) {
    int thr = 1 << shift;
    int ax = x < 0 ? -x : x;
    x = (ax >= thr) ? x : 0;
    return x >> shift;
}

// byte-pack helpers (byte j of result = k-value 4q+j)
__device__ __forceinline__ int pack_hi(int4 u) {
    return ((u.x >> 6) & 255) | (((u.y >> 6) & 255) << 8) |
           (((u.z >> 6) & 255) << 16) | (((u.w >> 6) & 255) << 24);
}
__device__ __forceinline__ int pack_lo(int4 u) {
    return (u.x & 63) | ((u.y & 63) << 8) | ((u.z & 63) << 16) | ((u.w & 63) << 24);
}
__device__ __forceinline__ int pack_b(int4 u) {
    return (u.x & 255) | ((u.y & 255) << 8) | ((u.z & 255) << 16) | ((u.w & 255) << 24);
}

// ---------------- Stage 1: sum-pool over L, dead_shift(4) ---- (unchanged) ----
__global__ __launch_bounds__(256) void pool_kernel(const int* __restrict__ x,
                                                   int* __restrict__ acc) {
    int wave = threadIdx.x >> 6;
    int lane = threadIdx.x & 63;
    int g = lane >> 4;
    int j = lane & 15;
    long long rowBase = ((long long)blockIdx.x * 4 + wave) * 8;
    const int* pA = x + (rowBase + g) * (long long)LL;
    const int* pB = x + (rowBase + 4 + g) * (long long)LL;

    int4 v[8], u[8];
#pragma unroll
    for (int c = 0; c < 8; ++c) v[c] = *(const int4*)(pA + c * 64 + j * 4);
#pragma unroll
    for (int c = 0; c < 8; ++c) u[c] = *(const int4*)(pB + c * 64 + j * 4);

    int sA = 0, sB = 0;
#pragma unroll
    for (int c = 0; c < 8; ++c) sA += v[c].x + v[c].y + v[c].z + v[c].w;
#pragma unroll
    for (int c = 0; c < 8; ++c) sB += u[c].x + u[c].y + u[c].z + u[c].w;

    sA += __shfl_xor(sA, 1, 64);  sB += __shfl_xor(sB, 1, 64);
    sA += __shfl_xor(sA, 2, 64);  sB += __shfl_xor(sB, 2, 64);
    sA += __shfl_xor(sA, 4, 64);  sB += __shfl_xor(sB, 4, 64);
    sA += __shfl_xor(sA, 8, 64);  sB += __shfl_xor(sB, 8, 64);

    if (j == 0) {
        acc[rowBase + g]     = dead_shift_i(sA, FINAL_SHIFT);
        acc[rowBase + 4 + g] = dead_shift_i(sB, FINAL_SHIFT);
    }
}

// ---------------- Stage 2: i8-dot4 GEMM, K-split partials ----------------
// acc (13-bit) split hi=acc>>6, lo=acc&63; W is 8-bit. Inline-packed into LDS
// at stage time. Thread tile 4b x 8n; per kk16: 16 ds_read_b128 feed 1024 MACs.
__global__ __launch_bounds__(256) void gemm_kernel(const int* __restrict__ acc,
                                                   const int* __restrict__ w,
                                                   int* __restrict__ partial,
                                                   int kch) {
    __shared__ int As[TBB][ASTR];    // [b][0..15]=hi dwords, [16..31]=lo dwords
    __shared__ int Ws[NKQ][WSTR];    // [kq][n] packed W dwords

    int b0 = blockIdx.x * TBB;
    int n0 = blockIdx.y * TNN;
    int kbase = blockIdx.z * kch;

    int t   = threadIdx.x;
    int tx4 = (t & 15) * 4;          // n quad base
    int ty4 = (t >> 4) * 4;          // b quad base

    int rH[4][8], rL[4][8];
#pragma unroll
    for (int bi = 0; bi < 4; ++bi)
#pragma unroll
        for (int j = 0; j < 8; ++j) { rH[bi][j] = 0; rL[bi][j] = 0; }

    for (int k0 = kbase; k0 < kbase + kch; k0 += BK) {
        // --- stage A: 64b x 64k int32 -> packed hi/lo dwords ---
        {
            int b   = t >> 2;                 // 0..63
            int kq0 = (t & 3) * 4;            // packed dword base: 0,4,8,12
            const int* src = acc + (long long)(b0 + b) * CC + k0 + kq0 * 4;
            int4 u0 = *(const int4*)(src + 0);
            int4 u1 = *(const int4*)(src + 4);
            int4 u2 = *(const int4*)(src + 8);
            int4 u3 = *(const int4*)(src + 12);
            *(int4*)&As[b][kq0]      = make_int4(pack_hi(u0), pack_hi(u1), pack_hi(u2), pack_hi(u3));
            *(int4*)&As[b][16 + kq0] = make_int4(pack_lo(u0), pack_lo(u1), pack_lo(u2), pack_lo(u3));
        }
        // --- stage W: 128n x 64k int32 -> Ws[kq][n] packed; coalesced reads ---
        {
            int jq = t & 15;                  // kq index = lane's int4 position
            int ng = t >> 4;                  // 0..15
#pragma unroll
            for (int rep = 0; rep < 8; ++rep) {
                int n  = rep * 16 + ng;       // 0..127
                int nn = n0 + n;
                int4 u = make_int4(0, 0, 0, 0);
                if (nn < NN) u = *(const int4*)(w + (long long)nn * CC + k0 + jq * 4);
                Ws[jq][n] = pack_b(u);
            }
        }
        __syncthreads();

#pragma unroll
        for (int q4 = 0; q4 < NKQ; q4 += 4) {
            int4 aH[4], aL[4];
#pragma unroll
            for (int bi = 0; bi < 4; ++bi) {
                aH[bi] = *(const int4*)&As[ty4 + bi][q4];
                aL[bi] = *(const int4*)&As[ty4 + bi][16 + q4];
            }
#pragma unroll
            for (int q = 0; q < 4; ++q) {
                int4 w0 = *(const int4*)&Ws[q4 + q][tx4];
                int4 w1 = *(const int4*)&Ws[q4 + q][64 + tx4];
#pragma unroll
                for (int bi = 0; bi < 4; ++bi) {
                    int ah = (q == 0) ? aH[bi].x : (q == 1) ? aH[bi].y
                           : (q == 2) ? aH[bi].z : aH[bi].w;
                    int al = (q == 0) ? aL[bi].x : (q == 1) ? aL[bi].y
                           : (q == 2) ? aL[bi].z : aL[bi].w;
                    rH[bi][0] = DOT4(ah, w0.x, rH[bi][0]);
                    rH[bi][1] = DOT4(ah, w0.y, rH[bi][1]);
                    rH[bi][2] = DOT4(ah, w0.z, rH[bi][2]);
                    rH[bi][3] = DOT4(ah, w0.w, rH[bi][3]);
                    rH[bi][4] = DOT4(ah, w1.x, rH[bi][4]);
                    rH[bi][5] = DOT4(ah, w1.y, rH[bi][5]);
                    rH[bi][6] = DOT4(ah, w1.z, rH[bi][6]);
                    rH[bi][7] = DOT4(ah, w1.w, rH[bi][7]);
                    rL[bi][0] = DOT4(al, w0.x, rL[bi][0]);
                    rL[bi][1] = DOT4(al, w0.y, rL[bi][1]);
                    rL[bi][2] = DOT4(al, w0.z, rL[bi][2]);
                    rL[bi][3] = DOT4(al, w0.w, rL[bi][3]);
                    rL[bi][4] = DOT4(al, w1.x, rL[bi][4]);
                    rL[bi][5] = DOT4(al, w1.y, rL[bi][5]);
                    rL[bi][6] = DOT4(al, w1.z, rL[bi][6]);
                    rL[bi][7] = DOT4(al, w1.w, rL[bi][7]);
                }
            }
        }
        __syncthreads();
    }

    long long base = (long long)blockIdx.z * BB * NN;
#pragma unroll
    for (int bi = 0; bi < 4; ++bi) {
        int b = b0 + ty4 + bi;
#pragma unroll
        for (int j = 0; j < 8; ++j) {
            int n = n0 + ((j < 4) ? (tx4 + j) : (64 + tx4 + (j - 4)));
            if (n < NN)
                partial[base + (long long)b * NN + n] = (rH[bi][j] << 6) + rL[bi][j];
        }
    }
}

// ---------------- Stage 3: reduce K-splits, dead_shift(11), clamp ----------------
__global__ __launch_bounds__(256) void epilogue_kernel(const int* __restrict__ partial,
                                                       int* __restrict__ out, int z) {
    int idx = blockIdx.x * 256 + threadIdx.x;
    if (idx >= BB * NN) return;
    int s = 0;
    for (int i = 0; i < z; ++i) s += partial[(long long)i * BB * NN + idx];
    int v = dead_shift_i(s, FC_SHIFT);
    v = min(127, max(-128, v));
    out[idx] = v;
}

extern "C" void kernel_launch(void* const* d_in, const int* in_sizes, int n_in,
                              void* d_out, int out_size, void* d_ws, size_t ws_size,
                              hipStream_t stream) {
    const int* x = (const int*)d_in[0];     // (B, C, L) int32
    const int* w = (const int*)d_in[1];     // (N, C) int32
    int* out = (int*)d_out;                 // (B, N) int32 values in [-128,127]

    int* acc     = (int*)d_ws;              // B*C ints = 2 MB
    int* partial = acc + (size_t)BB * CC;   // Z*B*N ints

    size_t accBytes = (size_t)BB * CC * 4;
    int Z = 8;                              // 8 -> 10 MB total ws
    while (Z > 1 && ws_size < accBytes + (size_t)Z * BB * NN * 4) Z >>= 1;
    int kch = CC / Z;

    pool_kernel<<<(BB * CC) / 32, 256, 0, stream>>>(x, acc);

    dim3 g2(BB / TBB, (NN + TNN - 1) / TNN, Z);   // (4, 8, Z) = 256 blocks at Z=8
    gemm_kernel<<<g2, 256, 0, stream>>>(acc, w, partial, kch);

    epilogue_kernel<<<(BB * NN + 255) / 256, 256, 0, stream>>>(partial, out, Z);
}

// Round 6
// 205.265 us; speedup vs baseline: 1.5354x; 1.1039x over previous
//
#include <hip/hip_runtime.h>

// IntClassifier: sum-pool over L + dead_shift(4) -> int GEMM (i8 dot4, hi/lo split)
// -> dead_shift(11)+clamp -> int8 (as int32). B=256, C=2048, L=512, N=1000
#define BB 256
#define CC 2048
#define LL 512
#define NN 1000
#define FINAL_SHIFT 4
#define FC_SHIFT 11

// GEMM tiling
#define TBB 64       // b per block
#define TNN 128      // n per block
#define BK 64        // k per LDS stage
#define NKQ 16       // BK/4 packed dwords per row
#define ASTR 36      // As row stride: 16 hi + 16 lo + 4 pad
#define WSTR 132     // Ws row stride: 128 + 4 pad

// Pool persistence
#define PBLK 2048            // pool blocks (8/CU)
#define RPI  (PBLK * 32)     // rows per sweep: 4 waves x 8 rows x 2048 blocks = 65536
#define PITER (BB * CC / RPI) // 8 sweeps

typedef int v4i __attribute__((ext_vector_type(4)));

#if __has_builtin(__builtin_amdgcn_sdot4)
#define DOT4(a, b, c) __builtin_amdgcn_sdot4((a), (b), (c), false)
#else
static __device__ __forceinline__ int dot4_fb(int a, int b, int c) {
#pragma unroll
    for (int j = 0; j < 4; ++j) {
        int av = (a << (24 - 8 * j)) >> 24;
        int bv = (b << (24 - 8 * j)) >> 24;
        c += av * bv;
    }
    return c;
}
#define DOT4(a, b, c) dot4_fb((a), (b), (c))
#endif

__device__ __forceinline__ int dead_shift_i(int x, int shift) {
    int thr = 1 << shift;
    int ax = x < 0 ? -x : x;
    x = (ax >= thr) ? x : 0;
    return x >> shift;
}

// byte-pack helpers (byte j of result = k-value 4q+j)
__device__ __forceinline__ int pack_hi(int4 u) {
    return ((u.x >> 6) & 255) | (((u.y >> 6) & 255) << 8) |
           (((u.z >> 6) & 255) << 16) | (((u.w >> 6) & 255) << 24);
}
__device__ __forceinline__ int pack_lo(int4 u) {
    return (u.x & 63) | ((u.y & 63) << 8) | ((u.z & 63) << 16) | ((u.w & 63) << 24);
}
__device__ __forceinline__ int pack_b(int4 u) {
    return (u.x & 255) | ((u.y & 255) << 8) | ((u.z & 255) << 16) | ((u.w & 255) << 24);
}

// ---------------- Stage 1: persistent, pipelined sum-pool ----------------
// 2048 blocks x 8 sweeps. Each wave: 8 rows/sweep via 16-lane row groups.
// Software pipeline: sweep i's adds consume v[], then sweep i+1's 16 nt-loads
// issue BEFORE sweep i's shfl chain + store -> memory pipe never drains.
__global__ __launch_bounds__(256) void pool_kernel(const int* __restrict__ x,
                                                   int* __restrict__ acc) {
    int wave = threadIdx.x >> 6;
    int lane = threadIdx.x & 63;
    int g = lane >> 4;                 // row within quad
    int j = lane & 15;                 // lane within 16-lane row group

    long long rb = (long long)blockIdx.x * 32 + wave * 8;   // first sweep's row base

    v4i v[16];
    {
        const int* pA = x + (rb + g) * (long long)LL + j * 4;
        const int* pB = x + (rb + 4 + g) * (long long)LL + j * 4;
#pragma unroll
        for (int c = 0; c < 8; ++c) v[c]     = __builtin_nontemporal_load((const v4i*)(pA + c * 64));
#pragma unroll
        for (int c = 0; c < 8; ++c) v[8 + c] = __builtin_nontemporal_load((const v4i*)(pB + c * 64));
    }

#pragma unroll
    for (int it = 0; it < PITER; ++it) {
        // reduce current buffers (consumes v[])
        int sA = 0, sB = 0;
#pragma unroll
        for (int c = 0; c < 8; ++c) sA += v[c].x + v[c].y + v[c].z + v[c].w;
#pragma unroll
        for (int c = 0; c < 8; ++c) sB += v[8 + c].x + v[8 + c].y + v[8 + c].z + v[8 + c].w;

        // issue next sweep's loads before the dependent shfl/store tail
        long long rbn = rb + RPI;
        if (it + 1 < PITER) {
            const int* pA = x + (rbn + g) * (long long)LL + j * 4;
            const int* pB = x + (rbn + 4 + g) * (long long)LL + j * 4;
#pragma unroll
            for (int c = 0; c < 8; ++c) v[c]     = __builtin_nontemporal_load((const v4i*)(pA + c * 64));
#pragma unroll
            for (int c = 0; c < 8; ++c) v[8 + c] = __builtin_nontemporal_load((const v4i*)(pB + c * 64));
        }

        sA += __shfl_xor(sA, 1, 64);  sB += __shfl_xor(sB, 1, 64);
        sA += __shfl_xor(sA, 2, 64);  sB += __shfl_xor(sB, 2, 64);
        sA += __shfl_xor(sA, 4, 64);  sB += __shfl_xor(sB, 4, 64);
        sA += __shfl_xor(sA, 8, 64);  sB += __shfl_xor(sB, 8, 64);

        if (j == 0) {
            acc[rb + g]     = dead_shift_i(sA, FINAL_SHIFT);
            acc[rb + 4 + g] = dead_shift_i(sB, FINAL_SHIFT);
        }
        rb = rbn;
    }
}

// ---------------- Stage 2: i8-dot4 GEMM, K-split partials ---- (unchanged) ----
__global__ __launch_bounds__(256) void gemm_kernel(const int* __restrict__ acc,
                                                   const int* __restrict__ w,
                                                   int* __restrict__ partial,
                                                   int kch) {
    __shared__ int As[TBB][ASTR];    // [b][0..15]=hi dwords, [16..31]=lo dwords
    __shared__ int Ws[NKQ][WSTR];    // [kq][n] packed W dwords

    int b0 = blockIdx.x * TBB;
    int n0 = blockIdx.y * TNN;
    int kbase = blockIdx.z * kch;

    int t   = threadIdx.x;
    int tx4 = (t & 15) * 4;
    int ty4 = (t >> 4) * 4;

    int rH[4][8], rL[4][8];
#pragma unroll
    for (int bi = 0; bi < 4; ++bi)
#pragma unroll
        for (int j = 0; j < 8; ++j) { rH[bi][j] = 0; rL[bi][j] = 0; }

    for (int k0 = kbase; k0 < kbase + kch; k0 += BK) {
        {
            int b   = t >> 2;
            int kq0 = (t & 3) * 4;
            const int* src = acc + (long long)(b0 + b) * CC + k0 + kq0 * 4;
            int4 u0 = *(const int4*)(src + 0);
            int4 u1 = *(const int4*)(src + 4);
            int4 u2 = *(const int4*)(src + 8);
            int4 u3 = *(const int4*)(src + 12);
            *(int4*)&As[b][kq0]      = make_int4(pack_hi(u0), pack_hi(u1), pack_hi(u2), pack_hi(u3));
            *(int4*)&As[b][16 + kq0] = make_int4(pack_lo(u0), pack_lo(u1), pack_lo(u2), pack_lo(u3));
        }
        {
            int jq = t & 15;
            int ng = t >> 4;
#pragma unroll
            for (int rep = 0; rep < 8; ++rep) {
                int n  = rep * 16 + ng;
                int nn = n0 + n;
                int4 u = make_int4(0, 0, 0, 0);
                if (nn < NN) u = *(const int4*)(w + (long long)nn * CC + k0 + jq * 4);
                Ws[jq][n] = pack_b(u);
            }
        }
        __syncthreads();

#pragma unroll
        for (int q4 = 0; q4 < NKQ; q4 += 4) {
            int4 aH[4], aL[4];
#pragma unroll
            for (int bi = 0; bi < 4; ++bi) {
                aH[bi] = *(const int4*)&As[ty4 + bi][q4];
                aL[bi] = *(const int4*)&As[ty4 + bi][16 + q4];
            }
#pragma unroll
            for (int q = 0; q < 4; ++q) {
                int4 w0 = *(const int4*)&Ws[q4 + q][tx4];
                int4 w1 = *(const int4*)&Ws[q4 + q][64 + tx4];
#pragma unroll
                for (int bi = 0; bi < 4; ++bi) {
                    int ah = (q == 0) ? aH[bi].x : (q == 1) ? aH[bi].y
                           : (q == 2) ? aH[bi].z : aH[bi].w;
                    int al = (q == 0) ? aL[bi].x : (q == 1) ? aL[bi].y
                           : (q == 2) ? aL[bi].z : aL[bi].w;
                    rH[bi][0] = DOT4(ah, w0.x, rH[bi][0]);
                    rH[bi][1] = DOT4(ah, w0.y, rH[bi][1]);
                    rH[bi][2] = DOT4(ah, w0.z, rH[bi][2]);
                    rH[bi][3] = DOT4(ah, w0.w, rH[bi][3]);
                    rH[bi][4] = DOT4(ah, w1.x, rH[bi][4]);
                    rH[bi][5] = DOT4(ah, w1.y, rH[bi][5]);
                    rH[bi][6] = DOT4(ah, w1.z, rH[bi][6]);
                    rH[bi][7] = DOT4(ah, w1.w, rH[bi][7]);
                    rL[bi][0] = DOT4(al, w0.x, rL[bi][0]);
                    rL[bi][1] = DOT4(al, w0.y, rL[bi][1]);
                    rL[bi][2] = DOT4(al, w0.z, rL[bi][2]);
                    rL[bi][3] = DOT4(al, w0.w, rL[bi][3]);
                    rL[bi][4] = DOT4(al, w1.x, rL[bi][4]);
                    rL[bi][5] = DOT4(al, w1.y, rL[bi][5]);
                    rL[bi][6] = DOT4(al, w1.z, rL[bi][6]);
                    rL[bi][7] = DOT4(al, w1.w, rL[bi][7]);
                }
            }
        }
        __syncthreads();
    }

    long long base = (long long)blockIdx.z * BB * NN;
#pragma unroll
    for (int bi = 0; bi < 4; ++bi) {
        int b = b0 + ty4 + bi;
#pragma unroll
        for (int j = 0; j < 8; ++j) {
            int n = n0 + ((j < 4) ? (tx4 + j) : (64 + tx4 + (j - 4)));
            if (n < NN)
                partial[base + (long long)b * NN + n] = (rH[bi][j] << 6) + rL[bi][j];
        }
    }
}

// ---------------- Stage 3: reduce K-splits, dead_shift(11), clamp ----------------
__global__ __launch_bounds__(256) void epilogue_kernel(const int* __restrict__ partial,
                                                       int* __restrict__ out, int z) {
    int idx = blockIdx.x * 256 + threadIdx.x;
    if (idx >= BB * NN) return;
    int s = 0;
    for (int i = 0; i < z; ++i) s += partial[(long long)i * BB * NN + idx];
    int v = dead_shift_i(s, FC_SHIFT);
    v = min(127, max(-128, v));
    out[idx] = v;
}

extern "C" void kernel_launch(void* const* d_in, const int* in_sizes, int n_in,
                              void* d_out, int out_size, void* d_ws, size_t ws_size,
                              hipStream_t stream) {
    const int* x = (const int*)d_in[0];     // (B, C, L) int32
    const int* w = (const int*)d_in[1];     // (N, C) int32
    int* out = (int*)d_out;                 // (B, N) int32 values in [-128,127]

    int* acc     = (int*)d_ws;              // B*C ints = 2 MB
    int* partial = acc + (size_t)BB * CC;   // Z*B*N ints

    size_t accBytes = (size_t)BB * CC * 4;
    int Z = 8;                              // 10 MB total ws
    while (Z > 1 && ws_size < accBytes + (size_t)Z * BB * NN * 4) Z >>= 1;
    int kch = CC / Z;

    pool_kernel<<<PBLK, 256, 0, stream>>>(x, acc);

    dim3 g2(BB / TBB, (NN + TNN - 1) / TNN, Z);   // (4, 8, Z) = 256 blocks at Z=8
    gemm_kernel<<<g2, 256, 0, stream>>>(acc, w, partial, kch);

    epilogue_kernel<<<(BB * NN + 255) / 256, 256, 0, stream>>>(partial, out, Z);
}

// Round 7
// 199.792 us; speedup vs baseline: 1.5775x; 1.0274x over previous
//
#include <hip/hip_runtime.h>

// IntClassifier: sum-pool over L + dead_shift(4) -> int GEMM (i8 dot4, hi/lo split)
// -> dead_shift(11)+clamp -> int8 (as int32). B=256, C=2048, L=512, N=1000
#define BB 256
#define CC 2048
#define LL 512
#define NN 1000
#define FINAL_SHIFT 4
#define FC_SHIFT 11

// GEMM tiling
#define TBB 64       // b per block
#define TNN 128      // n per block
#define BK 64        // k per LDS stage
#define NKQ 16       // BK/4 packed dwords per row
#define ASTR 36      // As row stride: 16 hi + 16 lo + 4 pad
#define WSTR 132     // Ws row stride: 128 + 4 pad

// Pool persistence: 2048 blocks x 16 sweeps; 4 rows per wave per sweep.
#define PBLK 2048
#define RPS  (PBLK * 16)        // rows per sweep: 4 waves x 4 rows x 2048 = 32768
#define PITER (BB * CC / RPS)   // 16 sweeps

typedef int v4i __attribute__((ext_vector_type(4)));

#if __has_builtin(__builtin_amdgcn_sdot4)
#define DOT4(a, b, c) __builtin_amdgcn_sdot4((a), (b), (c), false)
#else
static __device__ __forceinline__ int dot4_fb(int a, int b, int c) {
#pragma unroll
    for (int j = 0; j < 4; ++j) {
        int av = (a << (24 - 8 * j)) >> 24;
        int bv = (b << (24 - 8 * j)) >> 24;
        c += av * bv;
    }
    return c;
}
#define DOT4(a, b, c) dot4_fb((a), (b), (c))
#endif

__device__ __forceinline__ int dead_shift_i(int x, int shift) {
    int thr = 1 << shift;
    int ax = x < 0 ? -x : x;
    x = (ax >= thr) ? x : 0;
    return x >> shift;
}

// byte-pack helpers (byte j of result = k-value 4q+j)
__device__ __forceinline__ int pack_hi(int4 u) {
    return ((u.x >> 6) & 255) | (((u.y >> 6) & 255) << 8) |
           (((u.z >> 6) & 255) << 16) | (((u.w >> 6) & 255) << 24);
}
__device__ __forceinline__ int pack_lo(int4 u) {
    return (u.x & 63) | ((u.y & 63) << 8) | ((u.z & 63) << 16) | ((u.w & 63) << 24);
}
__device__ __forceinline__ int pack_b(int4 u) {
    return (u.x & 255) | ((u.y & 255) << 8) | ((u.z & 255) << 16) | ((u.w & 255) << 24);
}

// ---------------- Stage 1: persistent, pipelined sum-pool ----------------
// v[8] in flight (32 VGPR) + __launch_bounds__(256,8) -> VGPR<=64, 8 blocks/CU,
// all 2048 blocks resident (32 waves/CU). Next sweep's 8 nt-loads issue before
// the current sweep's shfl chain + store.
__global__ __launch_bounds__(256, 8) void pool_kernel(const int* __restrict__ x,
                                                      int* __restrict__ acc) {
    int wave = threadIdx.x >> 6;
    int lane = threadIdx.x & 63;
    int g = lane >> 4;                 // row within wave's quad
    int j = lane & 15;                 // lane within 16-lane row group

    long long rb = (long long)blockIdx.x * 16 + wave * 4;   // first sweep's row base

    v4i v[8];
    {
        const int* p = x + (rb + g) * (long long)LL + j * 4;
#pragma unroll
        for (int c = 0; c < 8; ++c) v[c] = __builtin_nontemporal_load((const v4i*)(p + c * 64));
    }

#pragma unroll
    for (int it = 0; it < PITER; ++it) {
        int s = 0;
#pragma unroll
        for (int c = 0; c < 8; ++c) s += v[c].x + v[c].y + v[c].z + v[c].w;

        // issue next sweep's loads before the dependent shfl/store tail
        long long rbn = rb + RPS;
        if (it + 1 < PITER) {
            const int* p = x + (rbn + g) * (long long)LL + j * 4;
#pragma unroll
            for (int c = 0; c < 8; ++c) v[c] = __builtin_nontemporal_load((const v4i*)(p + c * 64));
        }

        s += __shfl_xor(s, 1, 64);
        s += __shfl_xor(s, 2, 64);
        s += __shfl_xor(s, 4, 64);
        s += __shfl_xor(s, 8, 64);

        if (j == 0) acc[rb + g] = dead_shift_i(s, FINAL_SHIFT);
        rb = rbn;
    }
}

// ---------------- Stage 2: i8-dot4 GEMM, K-split partials ---- (unchanged) ----
__global__ __launch_bounds__(256) void gemm_kernel(const int* __restrict__ acc,
                                                   const int* __restrict__ w,
                                                   int* __restrict__ partial,
                                                   int kch) {
    __shared__ int As[TBB][ASTR];    // [b][0..15]=hi dwords, [16..31]=lo dwords
    __shared__ int Ws[NKQ][WSTR];    // [kq][n] packed W dwords

    int b0 = blockIdx.x * TBB;
    int n0 = blockIdx.y * TNN;
    int kbase = blockIdx.z * kch;

    int t   = threadIdx.x;
    int tx4 = (t & 15) * 4;
    int ty4 = (t >> 4) * 4;

    int rH[4][8], rL[4][8];
#pragma unroll
    for (int bi = 0; bi < 4; ++bi)
#pragma unroll
        for (int j = 0; j < 8; ++j) { rH[bi][j] = 0; rL[bi][j] = 0; }

    for (int k0 = kbase; k0 < kbase + kch; k0 += BK) {
        {
            int b   = t >> 2;
            int kq0 = (t & 3) * 4;
            const int* src = acc + (long long)(b0 + b) * CC + k0 + kq0 * 4;
            int4 u0 = *(const int4*)(src + 0);
            int4 u1 = *(const int4*)(src + 4);
            int4 u2 = *(const int4*)(src + 8);
            int4 u3 = *(const int4*)(src + 12);
            *(int4*)&As[b][kq0]      = make_int4(pack_hi(u0), pack_hi(u1), pack_hi(u2), pack_hi(u3));
            *(int4*)&As[b][16 + kq0] = make_int4(pack_lo(u0), pack_lo(u1), pack_lo(u2), pack_lo(u3));
        }
        {
            int jq = t & 15;
            int ng = t >> 4;
#pragma unroll
            for (int rep = 0; rep < 8; ++rep) {
                int n  = rep * 16 + ng;
                int nn = n0 + n;
                int4 u = make_int4(0, 0, 0, 0);
                if (nn < NN) u = *(const int4*)(w + (long long)nn * CC + k0 + jq * 4);
                Ws[jq][n] = pack_b(u);
            }
        }
        __syncthreads();

#pragma unroll
        for (int q4 = 0; q4 < NKQ; q4 += 4) {
            int4 aH[4], aL[4];
#pragma unroll
            for (int bi = 0; bi < 4; ++bi) {
                aH[bi] = *(const int4*)&As[ty4 + bi][q4];
                aL[bi] = *(const int4*)&As[ty4 + bi][16 + q4];
            }
#pragma unroll
            for (int q = 0; q < 4; ++q) {
                int4 w0 = *(const int4*)&Ws[q4 + q][tx4];
                int4 w1 = *(const int4*)&Ws[q4 + q][64 + tx4];
#pragma unroll
                for (int bi = 0; bi < 4; ++bi) {
                    int ah = (q == 0) ? aH[bi].x : (q == 1) ? aH[bi].y
                           : (q == 2) ? aH[bi].z : aH[bi].w;
                    int al = (q == 0) ? aL[bi].x : (q == 1) ? aL[bi].y
                           : (q == 2) ? aL[bi].z : aL[bi].w;
                    rH[bi][0] = DOT4(ah, w0.x, rH[bi][0]);
                    rH[bi][1] = DOT4(ah, w0.y, rH[bi][1]);
                    rH[bi][2] = DOT4(ah, w0.z, rH[bi][2]);
                    rH[bi][3] = DOT4(ah, w0.w, rH[bi][3]);
                    rH[bi][4] = DOT4(ah, w1.x, rH[bi][4]);
                    rH[bi][5] = DOT4(ah, w1.y, rH[bi][5]);
                    rH[bi][6] = DOT4(ah, w1.z, rH[bi][6]);
                    rH[bi][7] = DOT4(ah, w1.w, rH[bi][7]);
                    rL[bi][0] = DOT4(al, w0.x, rL[bi][0]);
                    rL[bi][1] = DOT4(al, w0.y, rL[bi][1]);
                    rL[bi][2] = DOT4(al, w0.z, rL[bi][2]);
                    rL[bi][3] = DOT4(al, w0.w, rL[bi][3]);
                    rL[bi][4] = DOT4(al, w1.x, rL[bi][4]);
                    rL[bi][5] = DOT4(al, w1.y, rL[bi][5]);
                    rL[bi][6] = DOT4(al, w1.z, rL[bi][6]);
                    rL[bi][7] = DOT4(al, w1.w, rL[bi][7]);
                }
            }
        }
        __syncthreads();
    }

    long long base = (long long)blockIdx.z * BB * NN;
#pragma unroll
    for (int bi = 0; bi < 4; ++bi) {
        int b = b0 + ty4 + bi;
#pragma unroll
        for (int j = 0; j < 8; ++j) {
            int n = n0 + ((j < 4) ? (tx4 + j) : (64 + tx4 + (j - 4)));
            if (n < NN)
                partial[base + (long long)b * NN + n] = (rH[bi][j] << 6) + rL[bi][j];
        }
    }
}

// ---------------- Stage 3: reduce K-splits, dead_shift(11), clamp ----------------
__global__ __launch_bounds__(256) void epilogue_kernel(const int* __restrict__ partial,
                                                       int* __restrict__ out, int z) {
    int idx = blockIdx.x * 256 + threadIdx.x;
    if (idx >= BB * NN) return;
    int s = 0;
    for (int i = 0; i < z; ++i) s += partial[(long long)i * BB * NN + idx];
    int v = dead_shift_i(s, FC_SHIFT);
    v = min(127, max(-128, v));
    out[idx] = v;
}

extern "C" void kernel_launch(void* const* d_in, const int* in_sizes, int n_in,
                              void* d_out, int out_size, void* d_ws, size_t ws_size,
                              hipStream_t stream) {
    const int* x = (const int*)d_in[0];     // (B, C, L) int32
    const int* w = (const int*)d_in[1];     // (N, C) int32
    int* out = (int*)d_out;                 // (B, N) int32 values in [-128,127]

    int* acc     = (int*)d_ws;              // B*C ints = 2 MB
    int* partial = acc + (size_t)BB * CC;   // Z*B*N ints

    size_t accBytes = (size_t)BB * CC * 4;
    int Z = 8;                              // 10 MB total ws
    while (Z > 1 && ws_size < accBytes + (size_t)Z * BB * NN * 4) Z >>= 1;
    int kch = CC / Z;

    pool_kernel<<<PBLK, 256, 0, stream>>>(x, acc);

    dim3 g2(BB / TBB, (NN + TNN - 1) / TNN, Z);   // (4, 8, Z) = 256 blocks at Z=8
    gemm_kernel<<<g2, 256, 0, stream>>>(acc, w, partial, kch);

    epilogue_kernel<<<(BB * NN + 255) / 256, 256, 0, stream>>>(partial, out, Z);
}